// Round 18
// baseline (341.292 us; speedup 1.0000x reference)
//
#include <hip/hip_runtime.h>
#include <hip/hip_bf16.h>
#include <math.h>

#define IN_CH 512
#define MID_CH 64
#define OUT_CH 40

typedef __attribute__((ext_vector_type(8))) short short8;
typedef __attribute__((ext_vector_type(4))) float f32x4;
typedef __attribute__((ext_vector_type(2))) float f32x2;

static __device__ __forceinline__ unsigned short f2bf(float f) {
    unsigned int u = __float_as_uint(f);
    u += 0x7fffu + ((u >> 16) & 1u);   // round-to-nearest-even on bf16 boundary
    return (unsigned short)(u >> 16);
}

// ---------------- fused: degree count (CB blocks) + init (rest) -------------------
// cnt must be zeroed by a preceding memset. init: esrc padfill, W1 prep, dummy rows.
__global__ void k_initcount(const float* __restrict__ W1, unsigned short* __restrict__ w1f,
                            const int* __restrict__ dst, int* __restrict__ cnt,
                            int* __restrict__ esrc, int dummy_off, int epad,
                            unsigned char* __restrict__ h1q, unsigned char* __restrict__ h2q,
                            int N, int E, int CB) {
    int b = blockIdx.x;
    if (b < CB) {
        // ---- count path: grid-stride, coalesced dst reads, scattered atomics ----
        int stride = CB * 256;
        for (int e = b * 256 + (int)threadIdx.x; e < E; e += stride)
            atomicAdd(&cnt[dst[e]], 1);
        return;
    }
    int i = (b - CB) * 256 + threadIdx.x;
    if (i < epad) esrc[i] = dummy_off;
    if (i < IN_CH * MID_CH) {
        int k = i >> 6, c = i & 63;
        w1f[(((k >> 3) * 64) + c) * 8 + (k & 7)] = f2bf(W1[i]);
    }
    if (i < 64) {
        h1q[(size_t)N * 64 + i] = 0;
        h2q[(size_t)N * 64 + i] = 0;
    }
}

// ---------------- CSR scan over PADDED degrees (round up to 4); dis from real deg --
__global__ void k_scanA(const int* __restrict__ cnt, int* __restrict__ rowptr,
                        int* __restrict__ bsum, float* __restrict__ dis, int N) {
    __shared__ int wsum[16];
    int i = blockIdx.x * 1024 + threadIdx.x;
    int lane = threadIdx.x & 63, wv = threadIdx.x >> 6;
    int v = (i < N) ? cnt[i] : 0;
    if (i < N) dis[i] = rsqrtf((float)v + 1.0f);
    int x = (v + 3) & ~3;                      // padded degree (mult of 4)
    #pragma unroll
    for (int off = 1; off < 64; off <<= 1) {
        int t = __shfl_up(x, off);
        if (lane >= off) x += t;
    }
    if (lane == 63) wsum[wv] = x;
    __syncthreads();
    if (wv == 0 && lane < 16) {
        int own = wsum[lane];
        int y = own;
        #pragma unroll
        for (int off = 1; off < 16; off <<= 1) {
            int t = __shfl_up(y, off);
            if (lane >= off) y += t;
        }
        wsum[lane] = y - own;
        if (lane == 15) bsum[blockIdx.x] = y;
    }
    __syncthreads();
    if (i < N) rowptr[i + 1] = x + wsum[wv];
}

__global__ void k_scanB(int* __restrict__ bsum, int nb) {
    __shared__ int tmp[2];
    int lane = threadIdx.x & 63, wv = threadIdx.x >> 6;
    int v = (threadIdx.x < nb) ? bsum[threadIdx.x] : 0;
    int x = v;
    #pragma unroll
    for (int off = 1; off < 64; off <<= 1) {
        int t = __shfl_up(x, off);
        if (lane >= off) x += t;
    }
    if (lane == 63) tmp[wv] = x;
    __syncthreads();
    int add = (wv == 1) ? tmp[0] : 0;
    if (threadIdx.x < nb) bsum[threadIdx.x] = x - v + add;
}

// C: add chunk offsets; ALSO initialize cursor cur[] = rowptr[]
__global__ void k_scanC(int* __restrict__ rowptr, int* __restrict__ cur,
                        const int* __restrict__ bsum, int N) {
    int i = blockIdx.x * 1024 + threadIdx.x;
    if (i < N) {
        int v = rowptr[i + 1] + bsum[blockIdx.x];
        rowptr[i + 1] = v;
        cur[i + 1] = v;
    }
    if (i == 0) { rowptr[0] = 0; cur[0] = 0; }
}

// ---------------- fused: CSR fill (first FB blocks, unpartitioned) + GEMM1 --------
// blocks [0,FB): fill a contiguous E/FB chunk, one pass (each edge touched once);
// blocks >=FB: gemm, 256 thr = 4 waves, 64 rows x 64 cols, no LDS (w1f from L2),
// depth-2 X prefetch ring; h1q = fp8(dis[row] * (X @ W1)).   [R12-proven structure]
__launch_bounds__(256, 6)
__global__ void k_fillgemm(const float* __restrict__ X, const unsigned short* __restrict__ w1f,
                           const float* __restrict__ dis, unsigned char* __restrict__ h1q,
                           int N, int FB,
                           const int* __restrict__ src, const int* __restrict__ dst,
                           int* __restrict__ cur, int* __restrict__ esrc, int E) {
    if ((int)blockIdx.x < FB) {
        // ---- fill path: contiguous chunk, no partition filter ----
        int ech = (E + FB - 1) / FB;
        int e0 = blockIdx.x * ech;
        int e1 = e0 + ech; if (e1 > E) e1 = E;
        for (int e = e0 + (int)threadIdx.x; e < e1; e += 256) {
            int p = atomicAdd(&cur[dst[e]], 1);
            esrc[p] = src[e] << 6;      // byte offset of 64-B fp8 row
        }
        return;
    }

    // ---- gemm path ----
    int wave = threadIdx.x >> 6, lane = threadIdx.x & 63;
    int gb = blockIdx.x - FB;
    int rbase = gb * 64 + wave * 16;
    int g = lane >> 4;
    int arow = rbase + (lane & 15);
    if (arow > N - 1) arow = N - 1;              // clamp loads; stores are guarded
    const float* xp = X + (size_t)arow * IN_CH + g * 8;
    const short8* wb = (const short8*)w1f;

    f32x4 acc[4];
    #pragma unroll
    for (int i = 0; i < 4; ++i) acc[i] = (f32x4){0.f, 0.f, 0.f, 0.f};

    float4 bx0[2], bx1[2];
    {
        const float4* p0 = (const float4*)(xp);
        const float4* p1 = (const float4*)(xp + 32);
        bx0[0] = p0[0]; bx1[0] = p0[1];
        bx0[1] = p1[0]; bx1[1] = p1[1];
    }

    #pragma unroll
    for (int ks = 0; ks < 16; ++ks) {
        float4 x0 = bx0[ks & 1], x1 = bx1[ks & 1];
        if (ks < 14) {
            const float4* p = (const float4*)(xp + (ks + 2) * 32);
            bx0[ks & 1] = p[0]; bx1[ks & 1] = p[1];
        }
        short8 a;
        a[0] = (short)f2bf(x0.x); a[1] = (short)f2bf(x0.y);
        a[2] = (short)f2bf(x0.z); a[3] = (short)f2bf(x0.w);
        a[4] = (short)f2bf(x1.x); a[5] = (short)f2bf(x1.y);
        a[6] = (short)f2bf(x1.z); a[7] = (short)f2bf(x1.w);

        int cibase = (ks * 4 + g) * 64 + (lane & 15);
        #pragma unroll
        for (int ct = 0; ct < 4; ++ct) {
            short8 b = wb[cibase + ct * 16];
            acc[ct] = __builtin_amdgcn_mfma_f32_16x16x32_bf16(a, b, acc[ct], 0, 0, 0);
        }
    }

    // D layout: col = lane&15, row = (lane>>4)*4 + reg
    int colb = lane & 15;
    int rquad = rbase + (lane >> 4) * 4;
    #pragma unroll
    for (int ct = 0; ct < 4; ++ct) {
        #pragma unroll
        for (int r = 0; r < 4; ++r) {
            int row = rquad + r;
            if (row < N) {
                float v = acc[ct][r] * dis[row];
                unsigned q = __builtin_amdgcn_cvt_pk_fp8_f32(v, v, 0, false);
                h1q[(size_t)row * 64 + ct * 16 + colb] = (unsigned char)q;
            }
        }
    }
}

// ---- fp8 gather unpack: one u32 = 4 channels ----
#define AGG_UNPACK8(Q)                                              \
    {                                                               \
        f32x2 lo_ = __builtin_amdgcn_cvt_pk_f32_fp8((Q), false);    \
        f32x2 hi_ = __builtin_amdgcn_cvt_pk_f32_fp8((Q), true);     \
        acc[0] += lo_[0]; acc[1] += lo_[1];                         \
        acc[2] += hi_[0]; acc[3] += hi_[1];                         \
    }

// ---- shared gather core: 64-B rows, 4 edge-subgroups x 16 channel-quads ----
#define GATHER_CORE(HB)                                                 \
    f32x4 acc = (f32x4){0.f, 0.f, 0.f, 0.f};                            \
    for (int cbeg = beg; cbeg < end; cbeg += 64) {                      \
        int m = end - cbeg; if (m > 64) m = 64;  /* multiple of 4 */    \
        int soff = esrc[cbeg + lane];                                   \
        int k4n = m >> 2;                                               \
        int k4 = 0;                                                     \
        for (; k4 + 4 <= k4n; k4 += 4) {                                \
            int o0 = __shfl(soff, (k4 + 0) * 4 + g);                    \
            int o1 = __shfl(soff, (k4 + 1) * 4 + g);                    \
            int o2 = __shfl(soff, (k4 + 2) * 4 + g);                    \
            int o3 = __shfl(soff, (k4 + 3) * 4 + g);                    \
            unsigned q0 = *(const unsigned*)((HB) + ((unsigned)o0 + cgoff)); \
            unsigned q1 = *(const unsigned*)((HB) + ((unsigned)o1 + cgoff)); \
            unsigned q2 = *(const unsigned*)((HB) + ((unsigned)o2 + cgoff)); \
            unsigned q3 = *(const unsigned*)((HB) + ((unsigned)o3 + cgoff)); \
            AGG_UNPACK8(q0) AGG_UNPACK8(q1) AGG_UNPACK8(q2) AGG_UNPACK8(q3) \
        }                                                               \
        for (; k4 < k4n; ++k4) {                                        \
            int o = __shfl(soff, k4 * 4 + g);                           \
            unsigned q = *(const unsigned*)((HB) + ((unsigned)o + cgoff)); \
            AGG_UNPACK8(q)                                              \
        }                                                               \
    }                                                                   \
    _Pragma("unroll")                                                   \
    for (int off = 32; off >= 16; off >>= 1) {                          \
        acc[0] += __shfl_xor(acc[0], off);                              \
        acc[1] += __shfl_xor(acc[1], off);                              \
        acc[2] += __shfl_xor(acc[2], off);                              \
        acc[3] += __shfl_xor(acc[3], off);                              \
    }

// ---------------- layer 1: gather + finish + elu (one wave per node) --------------
__launch_bounds__(256)
__global__ void k_agg1(const unsigned char* __restrict__ hq, const float* __restrict__ dis,
                       const int* __restrict__ rowptr, const int* __restrict__ esrc,
                       const float* __restrict__ b1, unsigned char* __restrict__ h2q,
                       int N) {
    int wv = threadIdx.x >> 6, lane = threadIdx.x & 63;
    int n = blockIdx.x * 4 + wv;
    if (n >= N) return;
    int g = lane >> 4, cg = lane & 15;
    int beg = rowptr[n], end = rowptr[n + 1];
    unsigned cgoff = (unsigned)(cg * 4);
    const char* hb = (const char*)hq;

    GATHER_CORE(hb)

    if (g == 0) {
        float dn = dis[n];
        unsigned qs = *(const unsigned*)(hb + ((unsigned)(n * 64) + cgoff));
        f32x2 slo = __builtin_amdgcn_cvt_pk_f32_fp8(qs, false);
        f32x2 shi = __builtin_amdgcn_cvt_pk_f32_fp8(qs, true);
        float4 b4 = *(const float4*)(b1 + cg * 4);
        float v0 = dn * (acc[0] + slo[0]) + b4.x;
        float v1 = dn * (acc[1] + slo[1]) + b4.y;
        float v2 = dn * (acc[2] + shi[0]) + b4.z;
        float v3 = dn * (acc[3] + shi[1]) + b4.w;
        v0 = v0 > 0.f ? v0 : expm1f(v0);
        v1 = v1 > 0.f ? v1 : expm1f(v1);
        v2 = v2 > 0.f ? v2 : expm1f(v2);
        v3 = v3 > 0.f ? v3 : expm1f(v3);
        unsigned w = __builtin_amdgcn_cvt_pk_fp8_f32(dn * v0, dn * v1, 0, false);
        w = __builtin_amdgcn_cvt_pk_fp8_f32(dn * v2, dn * v3, w, true);
        *(unsigned*)(h2q + (size_t)n * 64 + cg * 4) = w;
    }
}

// ---------------- layer 2: gather + GEMM2 + log_softmax ---------------------------
__launch_bounds__(256)
__global__ void k_agg2(const unsigned char* __restrict__ hq, const float* __restrict__ dis,
                       const int* __restrict__ rowptr, const int* __restrict__ esrc,
                       const float* __restrict__ W2, const float* __restrict__ b2,
                       float* __restrict__ out, int N) {
    __shared__ float w2l[MID_CH * OUT_CH];
    __shared__ float vl[4 * MID_CH];
    for (int f = threadIdx.x; f < MID_CH * OUT_CH; f += 256) w2l[f] = W2[f];
    __syncthreads();

    int wv = threadIdx.x >> 6, lane = threadIdx.x & 63;
    int n = blockIdx.x * 4 + wv;
    if (n >= N) return;
    int g = lane >> 4, cg = lane & 15;
    int beg = rowptr[n], end = rowptr[n + 1];
    unsigned cgoff = (unsigned)(cg * 4);
    const char* hb = (const char*)hq;

    GATHER_CORE(hb)

    if (g == 0) {
        float dn = dis[n];
        unsigned qs = *(const unsigned*)(hb + ((unsigned)(n * 64) + cgoff));
        f32x2 slo = __builtin_amdgcn_cvt_pk_f32_fp8(qs, false);
        f32x2 shi = __builtin_amdgcn_cvt_pk_f32_fp8(qs, true);
        float4 v;
        v.x = dn * (acc[0] + slo[0]);
        v.y = dn * (acc[1] + slo[1]);
        v.z = dn * (acc[2] + shi[0]);
        v.w = dn * (acc[3] + shi[1]);
        *(float4*)&vl[wv * 64 + cg * 4] = v;
    }

    float o = (lane < OUT_CH) ? b2[lane] : 0.f;
    const float* vrow = &vl[wv * 64];
    #pragma unroll 8
    for (int c = 0; c < MID_CH; ++c)
        o += vrow[c] * w2l[c * OUT_CH + lane];

    float mx = (lane < OUT_CH) ? o : -1e30f;
    #pragma unroll
    for (int off = 32; off > 0; off >>= 1) mx = fmaxf(mx, __shfl_xor(mx, off));
    float e = (lane < OUT_CH) ? expf(o - mx) : 0.f;
    float ssum = e;
    #pragma unroll
    for (int off = 32; off > 0; off >>= 1) ssum += __shfl_xor(ssum, off);
    if (lane < OUT_CH)
        out[(size_t)n * OUT_CH + lane] = o - mx - logf(ssum);
}

extern "C" void kernel_launch(void* const* d_in, const int* in_sizes, int n_in,
                              void* d_out, int out_size, void* d_ws, size_t ws_size,
                              hipStream_t stream) {
    const float* X  = (const float*)d_in[0];
    const int* adj  = (const int*)d_in[1];
    const float* W1 = (const float*)d_in[2];
    const float* b1 = (const float*)d_in[3];
    const float* W2 = (const float*)d_in[4];
    const float* b2 = (const float*)d_in[5];
    float* out = (float*)d_out;

    int N = in_sizes[0] / IN_CH;
    int E = in_sizes[1] / 2;
    const int* srcp = adj;
    const int* dstp = adj + E;
    int nchunk = (N + 1023) / 1024;              // 98 (<=128 required by scanB)
    int epad_max = E + 3 * N + 128;
    int FB = 1024;                               // fill blocks
    int GB = (N + 63) / 64;                      // gemm blocks (1563)
    int CB = 512;                                // count blocks

    char* ws = (char*)d_ws;
    size_t off = 0;
    int*   cnt    = (int*)(ws + off);  off += (size_t)N * sizeof(int);
    int*   cur    = (int*)(ws + off);  off += ((size_t)N + 8) * sizeof(int);
    float* dis    = (float*)(ws + off); off += (size_t)N * sizeof(float);
    int*   rowptr = (int*)(ws + off);  off += ((size_t)N + 8) * sizeof(int);
    int*   bsum   = (int*)(ws + off);  off += 128 * sizeof(int);
    int*   esrc   = (int*)(ws + off);  off += (size_t)epad_max * sizeof(int);
    unsigned short* w1f = (unsigned short*)(ws + off); off += (size_t)IN_CH * MID_CH * sizeof(unsigned short);
    unsigned char* h1q = (unsigned char*)(ws + off); off += (size_t)(N + 4) * MID_CH;
    unsigned char* h2q = (unsigned char*)(ws + off); off += (size_t)(N + 4) * MID_CH;

    hipMemsetAsync(cnt, 0, (size_t)N * sizeof(int), stream);
    int IB = (epad_max + 255) / 256;
    k_initcount<<<CB + IB, 256, 0, stream>>>(W1, w1f, dstp, cnt, esrc, N << 6,
                                             epad_max, h1q, h2q, N, E, CB);
    k_scanA<<<nchunk, 1024, 0, stream>>>(cnt, rowptr, bsum, dis, N);
    k_scanB<<<1, 128, 0, stream>>>(bsum, nchunk);
    k_scanC<<<nchunk, 1024, 0, stream>>>(rowptr, cur, bsum, N);

    k_fillgemm<<<FB + GB, 256, 0, stream>>>(X, w1f, dis, h1q, N, FB,
                                            srcp, dstp, cur, esrc, E);

    int nb = (N + 3) / 4;
    k_agg1<<<nb, 256, 0, stream>>>(h1q, dis, rowptr, esrc, b1, h2q, N);
    k_agg2<<<nb, 256, 0, stream>>>(h2q, dis, rowptr, esrc, W2, b2, out, N);
}

// Round 19
// 278.869 us; speedup vs baseline: 1.2238x; 1.2238x over previous
//
#include <hip/hip_runtime.h>
#include <hip/hip_bf16.h>
#include <math.h>

#define IN_CH 512
#define MID_CH 64
#define OUT_CH 40

typedef __attribute__((ext_vector_type(8))) short short8;
typedef __attribute__((ext_vector_type(4))) float f32x4;
typedef __attribute__((ext_vector_type(2))) float f32x2;

static __device__ __forceinline__ unsigned short f2bf(float f) {
    unsigned int u = __float_as_uint(f);
    u += 0x7fffu + ((u >> 16) & 1u);   // round-to-nearest-even on bf16 boundary
    return (unsigned short)(u >> 16);
}

// ---------------- fused init: cnt=0, W1 prep, esrc padfill, dummy rows ------------
__global__ void k_init(const float* __restrict__ W1, unsigned short* __restrict__ w1f,
                       int* __restrict__ cnt, int* __restrict__ esrc, int dummy_off,
                       int epad, unsigned char* __restrict__ h1q,
                       unsigned char* __restrict__ h2q, int N) {
    int i = blockIdx.x * 256 + threadIdx.x;
    if (i < epad) esrc[i] = dummy_off;
    if (i < N) cnt[i] = 0;
    if (i < IN_CH * MID_CH) {
        int k = i >> 6, c = i & 63;
        w1f[(((k >> 3) * 64) + c) * 8 + (k & 7)] = f2bf(W1[i]);
    }
    if (i < 64) {
        h1q[(size_t)N * 64 + i] = 0;
        h2q[(size_t)N * 64 + i] = 0;
    }
}

// ---------------- degree count + per-edge rank (atomic return value) --------------
__global__ void k_countrank(const int* __restrict__ dst, int* __restrict__ cnt,
                            int* __restrict__ rank, int E) {
    int e = blockIdx.x * blockDim.x + threadIdx.x;
    if (e < E) rank[e] = atomicAdd(&cnt[dst[e]], 1);
}

// ---------------- CSR scan over PADDED degrees (round up to 4); dis from real deg --
__global__ void k_scanA(const int* __restrict__ cnt, int* __restrict__ rowptr,
                        int* __restrict__ bsum, float* __restrict__ dis, int N) {
    __shared__ int wsum[16];
    int i = blockIdx.x * 1024 + threadIdx.x;
    int lane = threadIdx.x & 63, wv = threadIdx.x >> 6;
    int v = (i < N) ? cnt[i] : 0;
    if (i < N) dis[i] = rsqrtf((float)v + 1.0f);
    int x = (v + 3) & ~3;                      // padded degree (mult of 4)
    #pragma unroll
    for (int off = 1; off < 64; off <<= 1) {
        int t = __shfl_up(x, off);
        if (lane >= off) x += t;
    }
    if (lane == 63) wsum[wv] = x;
    __syncthreads();
    if (wv == 0 && lane < 16) {
        int own = wsum[lane];
        int y = own;
        #pragma unroll
        for (int off = 1; off < 16; off <<= 1) {
            int t = __shfl_up(y, off);
            if (lane >= off) y += t;
        }
        wsum[lane] = y - own;
        if (lane == 15) bsum[blockIdx.x] = y;
    }
    __syncthreads();
    if (i < N) rowptr[i + 1] = x + wsum[wv];
}

__global__ void k_scanB(int* __restrict__ bsum, int nb) {
    __shared__ int tmp[2];
    int lane = threadIdx.x & 63, wv = threadIdx.x >> 6;
    int v = (threadIdx.x < nb) ? bsum[threadIdx.x] : 0;
    int x = v;
    #pragma unroll
    for (int off = 1; off < 64; off <<= 1) {
        int t = __shfl_up(x, off);
        if (lane >= off) x += t;
    }
    if (lane == 63) tmp[wv] = x;
    __syncthreads();
    int add = (wv == 1) ? tmp[0] : 0;
    if (threadIdx.x < nb) bsum[threadIdx.x] = x - v + add;
}

// C: add chunk offsets
__global__ void k_scanC(int* __restrict__ rowptr, const int* __restrict__ bsum, int N) {
    int i = blockIdx.x * 1024 + threadIdx.x;
    if (i < N) rowptr[i + 1] += bsum[blockIdx.x];
    if (i == 0) rowptr[0] = 0;
}

// ---------------- fused: CSR fill (ATOMIC-FREE via rank) + GEMM1 ------------------
// blocks [0,FB): fill contiguous chunk: esrc[rowptr[dst]+rank] = src<<6 (no atomic);
// blocks >=FB: gemm, 256 thr = 4 waves, 64 rows x 64 cols, no LDS (w1f from L2),
// depth-2 X prefetch ring; h1q = fp8(dis[row] * (X @ W1)).   [R12-proven gemm path]
__launch_bounds__(256, 6)
__global__ void k_fillgemm(const float* __restrict__ X, const unsigned short* __restrict__ w1f,
                           const float* __restrict__ dis, unsigned char* __restrict__ h1q,
                           int N, int FB,
                           const int* __restrict__ src, const int* __restrict__ dst,
                           const int* __restrict__ rank, const int* __restrict__ rowptr,
                           int* __restrict__ esrc, int E) {
    if ((int)blockIdx.x < FB) {
        // ---- fill path: no atomics, pure pipelined loads + scattered store ----
        int ech = (E + FB - 1) / FB;
        int e0 = blockIdx.x * ech;
        int e1 = e0 + ech; if (e1 > E) e1 = E;
        for (int e = e0 + (int)threadIdx.x; e < e1; e += 256) {
            int d = dst[e];
            int p = rowptr[d] + rank[e];
            esrc[p] = src[e] << 6;      // byte offset of 64-B fp8 row
        }
        return;
    }

    // ---- gemm path ----
    int wave = threadIdx.x >> 6, lane = threadIdx.x & 63;
    int gb = blockIdx.x - FB;
    int rbase = gb * 64 + wave * 16;
    int g = lane >> 4;
    int arow = rbase + (lane & 15);
    if (arow > N - 1) arow = N - 1;              // clamp loads; stores are guarded
    const float* xp = X + (size_t)arow * IN_CH + g * 8;
    const short8* wb = (const short8*)w1f;

    f32x4 acc[4];
    #pragma unroll
    for (int i = 0; i < 4; ++i) acc[i] = (f32x4){0.f, 0.f, 0.f, 0.f};

    float4 bx0[2], bx1[2];
    {
        const float4* p0 = (const float4*)(xp);
        const float4* p1 = (const float4*)(xp + 32);
        bx0[0] = p0[0]; bx1[0] = p0[1];
        bx0[1] = p1[0]; bx1[1] = p1[1];
    }

    #pragma unroll
    for (int ks = 0; ks < 16; ++ks) {
        float4 x0 = bx0[ks & 1], x1 = bx1[ks & 1];
        if (ks < 14) {
            const float4* p = (const float4*)(xp + (ks + 2) * 32);
            bx0[ks & 1] = p[0]; bx1[ks & 1] = p[1];
        }
        short8 a;
        a[0] = (short)f2bf(x0.x); a[1] = (short)f2bf(x0.y);
        a[2] = (short)f2bf(x0.z); a[3] = (short)f2bf(x0.w);
        a[4] = (short)f2bf(x1.x); a[5] = (short)f2bf(x1.y);
        a[6] = (short)f2bf(x1.z); a[7] = (short)f2bf(x1.w);

        int cibase = (ks * 4 + g) * 64 + (lane & 15);
        #pragma unroll
        for (int ct = 0; ct < 4; ++ct) {
            short8 b = wb[cibase + ct * 16];
            acc[ct] = __builtin_amdgcn_mfma_f32_16x16x32_bf16(a, b, acc[ct], 0, 0, 0);
        }
    }

    // D layout: col = lane&15, row = (lane>>4)*4 + reg
    int colb = lane & 15;
    int rquad = rbase + (lane >> 4) * 4;
    #pragma unroll
    for (int ct = 0; ct < 4; ++ct) {
        #pragma unroll
        for (int r = 0; r < 4; ++r) {
            int row = rquad + r;
            if (row < N) {
                float v = acc[ct][r] * dis[row];
                unsigned q = __builtin_amdgcn_cvt_pk_fp8_f32(v, v, 0, false);
                h1q[(size_t)row * 64 + ct * 16 + colb] = (unsigned char)q;
            }
        }
    }
}

// ---- fp8 gather unpack: one u32 = 4 channels ----
#define AGG_UNPACK8(Q)                                              \
    {                                                               \
        f32x2 lo_ = __builtin_amdgcn_cvt_pk_f32_fp8((Q), false);    \
        f32x2 hi_ = __builtin_amdgcn_cvt_pk_f32_fp8((Q), true);     \
        acc[0] += lo_[0]; acc[1] += lo_[1];                         \
        acc[2] += hi_[0]; acc[3] += hi_[1];                         \
    }

// ---- shared gather core: 64-B rows, 4 edge-subgroups x 16 channel-quads ----
#define GATHER_CORE(HB)                                                 \
    f32x4 acc = (f32x4){0.f, 0.f, 0.f, 0.f};                            \
    for (int cbeg = beg; cbeg < end; cbeg += 64) {                      \
        int m = end - cbeg; if (m > 64) m = 64;  /* multiple of 4 */    \
        int soff = esrc[cbeg + lane];                                   \
        int k4n = m >> 2;                                               \
        int k4 = 0;                                                     \
        for (; k4 + 4 <= k4n; k4 += 4) {                                \
            int o0 = __shfl(soff, (k4 + 0) * 4 + g);                    \
            int o1 = __shfl(soff, (k4 + 1) * 4 + g);                    \
            int o2 = __shfl(soff, (k4 + 2) * 4 + g);                    \
            int o3 = __shfl(soff, (k4 + 3) * 4 + g);                    \
            unsigned q0 = *(const unsigned*)((HB) + ((unsigned)o0 + cgoff)); \
            unsigned q1 = *(const unsigned*)((HB) + ((unsigned)o1 + cgoff)); \
            unsigned q2 = *(const unsigned*)((HB) + ((unsigned)o2 + cgoff)); \
            unsigned q3 = *(const unsigned*)((HB) + ((unsigned)o3 + cgoff)); \
            AGG_UNPACK8(q0) AGG_UNPACK8(q1) AGG_UNPACK8(q2) AGG_UNPACK8(q3) \
        }                                                               \
        for (; k4 < k4n; ++k4) {                                        \
            int o = __shfl(soff, k4 * 4 + g);                           \
            unsigned q = *(const unsigned*)((HB) + ((unsigned)o + cgoff)); \
            AGG_UNPACK8(q)                                              \
        }                                                               \
    }                                                                   \
    _Pragma("unroll")                                                   \
    for (int off = 32; off >= 16; off >>= 1) {                          \
        acc[0] += __shfl_xor(acc[0], off);                              \
        acc[1] += __shfl_xor(acc[1], off);                              \
        acc[2] += __shfl_xor(acc[2], off);                              \
        acc[3] += __shfl_xor(acc[3], off);                              \
    }

// ---------------- layer 1: gather + finish + elu (one wave per node) --------------
__launch_bounds__(256)
__global__ void k_agg1(const unsigned char* __restrict__ hq, const float* __restrict__ dis,
                       const int* __restrict__ rowptr, const int* __restrict__ esrc,
                       const float* __restrict__ b1, unsigned char* __restrict__ h2q,
                       int N) {
    int wv = threadIdx.x >> 6, lane = threadIdx.x & 63;
    int n = blockIdx.x * 4 + wv;
    if (n >= N) return;
    int g = lane >> 4, cg = lane & 15;
    int beg = rowptr[n], end = rowptr[n + 1];
    unsigned cgoff = (unsigned)(cg * 4);
    const char* hb = (const char*)hq;

    GATHER_CORE(hb)

    if (g == 0) {
        float dn = dis[n];
        unsigned qs = *(const unsigned*)(hb + ((unsigned)(n * 64) + cgoff));
        f32x2 slo = __builtin_amdgcn_cvt_pk_f32_fp8(qs, false);
        f32x2 shi = __builtin_amdgcn_cvt_pk_f32_fp8(qs, true);
        float4 b4 = *(const float4*)(b1 + cg * 4);
        float v0 = dn * (acc[0] + slo[0]) + b4.x;
        float v1 = dn * (acc[1] + slo[1]) + b4.y;
        float v2 = dn * (acc[2] + shi[0]) + b4.z;
        float v3 = dn * (acc[3] + shi[1]) + b4.w;
        v0 = v0 > 0.f ? v0 : expm1f(v0);
        v1 = v1 > 0.f ? v1 : expm1f(v1);
        v2 = v2 > 0.f ? v2 : expm1f(v2);
        v3 = v3 > 0.f ? v3 : expm1f(v3);
        unsigned w = __builtin_amdgcn_cvt_pk_fp8_f32(dn * v0, dn * v1, 0, false);
        w = __builtin_amdgcn_cvt_pk_fp8_f32(dn * v2, dn * v3, w, true);
        *(unsigned*)(h2q + (size_t)n * 64 + cg * 4) = w;
    }
}

// ---------------- layer 2: gather + GEMM2 + log_softmax ---------------------------
__launch_bounds__(256)
__global__ void k_agg2(const unsigned char* __restrict__ hq, const float* __restrict__ dis,
                       const int* __restrict__ rowptr, const int* __restrict__ esrc,
                       const float* __restrict__ W2, const float* __restrict__ b2,
                       float* __restrict__ out, int N) {
    __shared__ float w2l[MID_CH * OUT_CH];
    __shared__ float vl[4 * MID_CH];
    for (int f = threadIdx.x; f < MID_CH * OUT_CH; f += 256) w2l[f] = W2[f];
    __syncthreads();

    int wv = threadIdx.x >> 6, lane = threadIdx.x & 63;
    int n = blockIdx.x * 4 + wv;
    if (n >= N) return;
    int g = lane >> 4, cg = lane & 15;
    int beg = rowptr[n], end = rowptr[n + 1];
    unsigned cgoff = (unsigned)(cg * 4);
    const char* hb = (const char*)hq;

    GATHER_CORE(hb)

    if (g == 0) {
        float dn = dis[n];
        unsigned qs = *(const unsigned*)(hb + ((unsigned)(n * 64) + cgoff));
        f32x2 slo = __builtin_amdgcn_cvt_pk_f32_fp8(qs, false);
        f32x2 shi = __builtin_amdgcn_cvt_pk_f32_fp8(qs, true);
        float4 v;
        v.x = dn * (acc[0] + slo[0]);
        v.y = dn * (acc[1] + slo[1]);
        v.z = dn * (acc[2] + shi[0]);
        v.w = dn * (acc[3] + shi[1]);
        *(float4*)&vl[wv * 64 + cg * 4] = v;
    }

    float o = (lane < OUT_CH) ? b2[lane] : 0.f;
    const float* vrow = &vl[wv * 64];
    #pragma unroll 8
    for (int c = 0; c < MID_CH; ++c)
        o += vrow[c] * w2l[c * OUT_CH + lane];

    float mx = (lane < OUT_CH) ? o : -1e30f;
    #pragma unroll
    for (int off = 32; off > 0; off >>= 1) mx = fmaxf(mx, __shfl_xor(mx, off));
    float e = (lane < OUT_CH) ? expf(o - mx) : 0.f;
    float ssum = e;
    #pragma unroll
    for (int off = 32; off > 0; off >>= 1) ssum += __shfl_xor(ssum, off);
    if (lane < OUT_CH)
        out[(size_t)n * OUT_CH + lane] = o - mx - logf(ssum);
}

extern "C" void kernel_launch(void* const* d_in, const int* in_sizes, int n_in,
                              void* d_out, int out_size, void* d_ws, size_t ws_size,
                              hipStream_t stream) {
    const float* X  = (const float*)d_in[0];
    const int* adj  = (const int*)d_in[1];
    const float* W1 = (const float*)d_in[2];
    const float* b1 = (const float*)d_in[3];
    const float* W2 = (const float*)d_in[4];
    const float* b2 = (const float*)d_in[5];
    float* out = (float*)d_out;

    int N = in_sizes[0] / IN_CH;
    int E = in_sizes[1] / 2;
    const int* srcp = adj;
    const int* dstp = adj + E;
    int nchunk = (N + 1023) / 1024;              // 98 (<=128 required by scanB)
    int epad_max = E + 3 * N + 128;
    int FB = 1024;                               // fill blocks
    int GB = (N + 63) / 64;                      // gemm blocks (1563)

    char* ws = (char*)d_ws;
    size_t off = 0;
    int*   cnt    = (int*)(ws + off);  off += (size_t)N * sizeof(int);
    int*   rank   = (int*)(ws + off);  off += (size_t)E * sizeof(int);
    float* dis    = (float*)(ws + off); off += (size_t)N * sizeof(float);
    int*   rowptr = (int*)(ws + off);  off += ((size_t)N + 8) * sizeof(int);
    int*   bsum   = (int*)(ws + off);  off += 128 * sizeof(int);
    int*   esrc   = (int*)(ws + off);  off += (size_t)epad_max * sizeof(int);
    unsigned short* w1f = (unsigned short*)(ws + off); off += (size_t)IN_CH * MID_CH * sizeof(unsigned short);
    unsigned char* h1q = (unsigned char*)(ws + off); off += (size_t)(N + 4) * MID_CH;
    unsigned char* h2q = (unsigned char*)(ws + off); off += (size_t)(N + 4) * MID_CH;

    k_init<<<(epad_max + 255) / 256, 256, 0, stream>>>(W1, w1f, cnt, esrc, N << 6,
                                                       epad_max, h1q, h2q, N);
    k_countrank<<<(E + 255) / 256, 256, 0, stream>>>(dstp, cnt, rank, E);
    k_scanA<<<nchunk, 1024, 0, stream>>>(cnt, rowptr, bsum, dis, N);
    k_scanB<<<1, 128, 0, stream>>>(bsum, nchunk);
    k_scanC<<<nchunk, 1024, 0, stream>>>(rowptr, bsum, N);

    k_fillgemm<<<FB + GB, 256, 0, stream>>>(X, w1f, dis, h1q, N, FB,
                                            srcp, dstp, rank, rowptr, esrc, E);

    int nb = (N + 3) / 4;
    k_agg1<<<nb, 256, 0, stream>>>(h1q, dis, rowptr, esrc, b1, h2q, N);
    k_agg2<<<nb, 256, 0, stream>>>(h2q, dis, rowptr, esrc, W2, b2, out, N);
}